// Round 10
// baseline (296.911 us; speedup 1.0000x reference)
//
#include <hip/hip_runtime.h>
#include <math.h>

typedef __bf16 bf16;
typedef __bf16 bf16x4 __attribute__((ext_vector_type(4)));
typedef __bf16 bf16x8 __attribute__((ext_vector_type(8)));
typedef float f32x4 __attribute__((ext_vector_type(4)));

#define MFMA(a, b, c) __builtin_amdgcn_mfma_f32_16x16x32_bf16(a, b, c, 0, 0, 0)
#define LOG2E 1.44269504088896340736f

// XOR-swizzled 64x64 bf16 tile (8 KB): elem (row, chunk8) at row*64 + ((ch^(row&7))*8).
// Staged via global_load_lds width=16 — linear LDS dest (wave-uniform base + lane*16),
// inverse-swizzled global source (rule #21: XOR involution -> frag() reads unchanged).
__device__ __forceinline__ void stage_async(bf16* __restrict__ T, const bf16* __restrict__ src,
                                            int rs, int t) {
#pragma unroll
    for (int i = 0; i < 2; ++i) {
        int u = i * 256 + t;                 // 16B chunk index in [0,512)
        int row = u >> 3, ch = u & 7;
        const bf16* g = src + (size_t)row * rs + ((ch ^ (row & 7)) << 3);
        bf16* lp = T + (size_t)(i * 256 + (t & 192)) * 8;   // wave-uniform base; HW adds lane*16
        __builtin_amdgcn_global_load_lds((__attribute__((address_space(1))) void*)g,
                                         (__attribute__((address_space(3))) void*)lp,
                                         16, 0, 0);
    }
}
__device__ __forceinline__ bf16x8 frag(const bf16* __restrict__ T, int row, int ch) {
    return *(const bf16x8*)&T[row * 64 + ((ch ^ (row & 7)) << 3)];
}
// P tile [16 rows][64 cols] with 16B-slot XOR swizzle; <=2-way conflicts (free).
__device__ __forceinline__ int pidx(int l, int k) {
    return l * 64 + ((((k >> 3) ^ (l & 7))) << 3) + (k & 7);
}

// ---------------- fused preprocessing (vectorized mask packing) --------------------
__global__ __launch_bounds__(256) void prep(
    const int* __restrict__ seqm, const int* __restrict__ spm,
    const float* __restrict__ x,
    const float* __restrict__ Wq, const float* __restrict__ Wk,
    const float* __restrict__ Wv, const float* __restrict__ Wo,
    unsigned* __restrict__ pseq, unsigned* __restrict__ psp,
    bf16* __restrict__ xb, bf16* __restrict__ Wb,
    bf16* __restrict__ Woh, bf16* __restrict__ Wol)
{
    int bid = blockIdx.x, t = threadIdx.x;
    if (bid < 2048) {
        int wave = t >> 6, lane = t & 63;
        int row = bid * 4 + wave;
        const int* src = (row < 4096) ? (seqm + (size_t)row * 2048)
                                      : (spm + (size_t)(row - 4096) * 2048);
        unsigned* dst = (row < 4096) ? (pseq + (size_t)row * 64)
                                     : (psp + (size_t)(row - 4096) * 64);
        const int4* s4 = (const int4*)src;
        unsigned bits = 0;
#pragma unroll
        for (int c = 0; c < 8; ++c) {
            int4 v = s4[lane * 8 + c];
            bits |= (v.x != 0 ? 1u : 0u) << (c * 4);
            bits |= (v.y != 0 ? 1u : 0u) << (c * 4 + 1);
            bits |= (v.z != 0 ? 1u : 0u) << (c * 4 + 2);
            bits |= (v.w != 0 ? 1u : 0u) << (c * 4 + 3);
        }
        dst[lane] = bits;
    } else if (bid < 3072) {
        int i = ((bid - 2048) * 256 + t) * 8;
        float4 a = *(const float4*)&x[i];
        float4 c = *(const float4*)&x[i + 4];
        float v[8] = {a.x, a.y, a.z, a.w, c.x, c.y, c.z, c.w};
        bf16x8 o;
#pragma unroll
        for (int u = 0; u < 8; ++u) o[u] = (bf16)v[u];
        *(bf16x8*)&xb[i] = o;
    } else {
        int zb = bid - 3072;
        int z = zb >> 7;
        int i = ((zb & 127) * 256 + t) * 8;
        const float* src = (z == 0) ? Wq : (z == 1) ? Wk : (z == 2) ? Wv : Wo;
        float4 a = *(const float4*)&src[i];
        float4 c = *(const float4*)&src[i + 4];
        float v[8] = {a.x, a.y, a.z, a.w, c.x, c.y, c.z, c.w};
        if (z < 3) {
            bf16x8 o;
#pragma unroll
            for (int u = 0; u < 8; ++u) o[u] = (bf16)v[u];
            *(bf16x8*)&Wb[(size_t)z * 262144 + i] = o;
        } else {
            bf16x8 oh, ol;
#pragma unroll
            for (int u = 0; u < 8; ++u) {
                bf16 hi = (bf16)v[u];
                oh[u] = hi;
                ol[u] = (bf16)(v[u] - (float)hi);
            }
            *(bf16x8*)&Woh[i] = oh;
            *(bf16x8*)&Wol[i] = ol;
        }
    }
}

// ---------------- fused QKV projection (R5-proven: single-barrier dbuf) ------------
__global__ __launch_bounds__(256) void gemm_qkv(
    const bf16* __restrict__ A, const bf16* __restrict__ Wb,
    bf16* __restrict__ Qg, bf16* __restrict__ Kg, bf16* __restrict__ Vt)
{
    __shared__ bf16 SM[24576];           // set s at SM + s*12288 (tiles +0,+4096,+8192)
    bf16* Lt = SM;                       // epilogue scratch, post-loop only
    int bid = blockIdx.x;
    int m0b = bid & 63;
    int rest = bid >> 6;
    int np = rest & 3, z = rest >> 2;
    const bf16* W = Wb + (size_t)z * 262144;
    float scale = (z == 0) ? (0.125f * LOG2E) : 1.0f;

    int t = threadIdx.x, wave = t >> 6, lane = t & 63, l = lane & 15, quad = lane >> 4;
    int m0 = m0b * 64 + wave * 16;
    int nb = np * 128;
    const bf16* Abase = A + (size_t)m0b * 64 * 512;
    const bf16* W0base = W + (size_t)nb * 512;
    const bf16* W1base = W + (size_t)(nb + 64) * 512;

    stage_async(SM, Abase, 512, t);
    stage_async(SM + 4096, W0base, 512, t);
    stage_async(SM + 8192, W1base, 512, t);

    f32x4 acc[8] = {};
    for (int ks = 0; ks < 8; ++ks) {
        bf16* set = SM + (ks & 1) * 12288;
        __syncthreads();                 // drains stage(ks) vmcnt + prior set reads
        if (ks < 7) {
            int k0 = (ks + 1) * 64;
            bf16* nset = SM + ((ks + 1) & 1) * 12288;
            stage_async(nset, Abase + k0, 512, t);
            stage_async(nset + 4096, W0base + k0, 512, t);
            stage_async(nset + 8192, W1base + k0, 512, t);
        }
        bf16x8 a0 = frag(set, wave * 16 + l, quad);
        bf16x8 a1 = frag(set, wave * 16 + l, 4 + quad);
#pragma unroll
        for (int nc = 0; nc < 4; ++nc) {
            bf16x8 b0 = frag(set + 4096, nc * 16 + l, quad);
            bf16x8 b1 = frag(set + 4096, nc * 16 + l, 4 + quad);
            acc[nc] = MFMA(a0, b0, acc[nc]);
            acc[nc] = MFMA(a1, b1, acc[nc]);
        }
#pragma unroll
        for (int nc = 0; nc < 4; ++nc) {
            bf16x8 b0 = frag(set + 8192, nc * 16 + l, quad);
            bf16x8 b1 = frag(set + 8192, nc * 16 + l, 4 + quad);
            acc[4 + nc] = MFMA(a0, b0, acc[4 + nc]);
            acc[4 + nc] = MFMA(a1, b1, acc[4 + nc]);
        }
    }
    if (z < 2) {
        bf16* out = (z == 0) ? Qg : Kg;
#pragma unroll
        for (int nc = 0; nc < 8; ++nc) {
#pragma unroll
            for (int r = 0; r < 4; ++r) {
                int m = m0 + quad * 4 + r;
                int feat = nb + nc * 16 + l;
                int b = m >> 11, tok = m & 2047, h = feat >> 6, d = feat & 63;
                out[(((size_t)(b * 8 + h)) * 2048 + tok) * 64 + d] = (bf16)(acc[nc][r] * scale);
            }
        }
    } else {
#pragma unroll
        for (int hh = 0; hh < 2; ++hh) {
            __syncthreads();
#pragma unroll
            for (int nc = 0; nc < 4; ++nc)
#pragma unroll
                for (int r = 0; r < 4; ++r)
                    Lt[(nc * 16 + l) * 72 + wave * 16 + quad * 4 + r] = (bf16)acc[hh * 4 + nc][r];
            __syncthreads();
            int d = t >> 2, seg = t & 3;
            int tok0 = m0b * 64;
            int b = tok0 >> 11, h = np * 2 + hh;
            bf16x8 o0, o1;
#pragma unroll
            for (int i = 0; i < 8; ++i) { o0[i] = Lt[d * 72 + seg * 16 + i]; o1[i] = Lt[d * 72 + seg * 16 + 8 + i]; }
            size_t base = ((size_t)(b * 8 + h) * 64 + d) * 2048 + (tok0 & 2047) + seg * 16;
            *(bf16x8*)&Vt[base] = o0;
            *(bf16x8*)&Vt[base + 8] = o1;
        }
    }
}

// ---------------- flash attention (R10: no-LDS-KV, zero barriers) ------------------
// grid 1024 = jc(1b) | it(5b) | bh(4b); 4 independent waves; LDS = P only (8 KB).
// K/V fragment reads are 16B-contiguous in global (K: [tok][64] row-major; V: [64][tok]
// d-major) and L1/L2-resident (512 KB per head) -> load directly global->reg.
// Deletes staging, double-buffers, and ALL barriers (P is per-wave; same-wave DS is
// ordered). Transient frags consumed in-iteration -> no loop-carried vr (the R8/R9
// spill cause). V loads issue before softmax; their latency hides under it.
__global__ __launch_bounds__(256) void attn_kernel(
    const bf16* __restrict__ Qg, const bf16* __restrict__ Kg, const bf16* __restrict__ Vt,
    const unsigned* __restrict__ pseq, const unsigned* __restrict__ psp,
    float* __restrict__ Opart, float* __restrict__ Lpart)
{
    __shared__ bf16 P[4][1024];
    int bid = blockIdx.x;
    int bh = bid & 15;                       // XCD = bid%8 -> K/V L2-resident
    int it = (bid >> 4) & 31;
    int jc = bid >> 9;                       // 0..1
    int i0 = it * 64;
    int b = bh >> 3, par = bh & 1;
    int t = threadIdx.x, rg = t >> 6, lane = t & 63, l = lane & 15, quad = lane >> 4;

    const bf16* Qp = Qg + ((size_t)bh * 2048 + i0 + rg * 16 + l) * 64;
    bf16x8 qf0 = *(const bf16x8*)&Qp[quad * 8];
    bf16x8 qf1 = *(const bf16x8*)&Qp[32 + quad * 8];

    bf16x8 ones;
#pragma unroll
    for (int i = 0; i < 8; ++i) ones[i] = (bf16)1.0f;
    const f32x4 fz = {0.f, 0.f, 0.f, 0.f};

    f32x4 o_acc[4] = {}, l_acc = {};

    int qrow = i0 + rg * 16 + l;
    const unsigned* seqp = pseq + (size_t)b * 131072 + (size_t)qrow * 64;
    const unsigned* sppp = psp + (size_t)par * 131072 + (size_t)qrow * 64;
    // per-lane fragment base pointers (16B-aligned):
    //   K frag (nc, half h): Kl[(j0 + nc*16)*64 + h*32]  == staged frag(KT,nc*16+l,4h+quad)
    //   V frag (dc, half h): Vl[dc*16*2048 + j0 + h*32]  == staged frag(VT,dc*16+l,4h+quad)
    const bf16* Kl = Kg + (size_t)bh * 2048 * 64 + (size_t)l * 64 + quad * 8;
    const bf16* Vl = Vt + (size_t)bh * 64 * 2048 + (size_t)l * 2048 + quad * 8;
    bf16* Pb = P[rg];

    const int NT = 16;
    int jlo = jc * 1024;

    for (int jj = 0; jj < NT; ++jj) {
        int j0 = jlo + jj * 64;
        uint2 mseq = *(const uint2*)&seqp[j0 >> 5];
        uint2 msp = *(const uint2*)&sppp[j0 >> 5];
        unsigned w0 = mseq.x & msp.x, w1 = mseq.y & msp.y;

        // QK(jj): K frags direct from global (L1/L2-hit)
        const bf16* Kj = Kl + (size_t)j0 * 64;
        f32x4 s[4];
        __builtin_amdgcn_s_setprio(1);
#pragma unroll
        for (int nc = 0; nc < 4; ++nc) {
            bf16x8 k0f = *(const bf16x8*)&Kj[(size_t)(nc * 16) * 64];
            bf16x8 k1f = *(const bf16x8*)&Kj[(size_t)(nc * 16) * 64 + 32];
            s[nc] = MFMA(k0f, qf0, fz);
            s[nc] = MFMA(k1f, qf1, s[nc]);
        }
        __builtin_amdgcn_s_setprio(0);

        // V frags issued now (independent of s); latency hides under softmax
        const bf16* Vj = Vl + j0;
        bf16x8 vr0 = *(const bf16x8*)&Vj[0];
        bf16x8 vr1 = *(const bf16x8*)&Vj[32];
        bf16x8 vr2 = *(const bf16x8*)&Vj[16 * 2048];
        bf16x8 vr3 = *(const bf16x8*)&Vj[16 * 2048 + 32];
        bf16x8 vr4 = *(const bf16x8*)&Vj[32 * 2048];
        bf16x8 vr5 = *(const bf16x8*)&Vj[32 * 2048 + 32];
        bf16x8 vr6 = *(const bf16x8*)&Vj[48 * 2048];
        bf16x8 vr7 = *(const bf16x8*)&Vj[48 * 2048 + 32];

        // fixed-max softmax: p = bit ? exp2(s) : 0 (Q pre-scaled by log2e)
#pragma unroll
        for (int nc = 0; nc < 4; ++nc) {
            unsigned w = (nc < 2) ? w0 : w1;
            int bbase = (nc & 1) * 16 + quad * 4;
            bf16x4 pv;
#pragma unroll
            for (int r = 0; r < 4; ++r) {
                float e = __builtin_amdgcn_exp2f(s[nc][r]);
                pv[r] = (bf16)(((w >> (bbase + r)) & 1u) ? e : 0.f);
            }
            *(bf16x4*)&Pb[pidx(l, nc * 16 + quad * 4)] = pv;
        }
        bf16x8 pa0 = *(const bf16x8*)&Pb[pidx(l, quad * 8)];
        bf16x8 pa1 = *(const bf16x8*)&Pb[pidx(l, 32 + quad * 8)];

        // PV(jj): all operands in registers
        __builtin_amdgcn_s_setprio(1);
        l_acc = MFMA(pa0, ones, l_acc);
        l_acc = MFMA(pa1, ones, l_acc);
        o_acc[0] = MFMA(pa0, vr0, o_acc[0]); o_acc[0] = MFMA(pa1, vr1, o_acc[0]);
        o_acc[1] = MFMA(pa0, vr2, o_acc[1]); o_acc[1] = MFMA(pa1, vr3, o_acc[1]);
        o_acc[2] = MFMA(pa0, vr4, o_acc[2]); o_acc[2] = MFMA(pa1, vr5, o_acc[2]);
        o_acc[3] = MFMA(pa0, vr6, o_acc[3]); o_acc[3] = MFMA(pa1, vr7, o_acc[3]);
        __builtin_amdgcn_s_setprio(0);
    }

    size_t pb = ((size_t)((bh * 32 + it) * 2 + jc)) * 4096;
#pragma unroll
    for (int dc = 0; dc < 4; ++dc)
#pragma unroll
        for (int r = 0; r < 4; ++r)
            Opart[pb + (size_t)(rg * 16 + quad * 4 + r) * 64 + dc * 16 + l] = o_acc[dc][r];
    if (l == 0) {
#pragma unroll
        for (int r = 0; r < 4; ++r)
            Lpart[((bh * 32 + it) * 2 + jc) * 64 + rg * 16 + quad * 4 + r] = l_acc[r];
    }
}

// ---------------- combine partials -> normalized split-bf16 O (jc=2, R6-proven) ----
__global__ __launch_bounds__(256) void attn_combine(
    const float* __restrict__ Opart, const float* __restrict__ Lpart,
    bf16* __restrict__ Oh, bf16* __restrict__ Ol)
{
    int blk = blockIdx.x;
    int bh = blk >> 5, it = blk & 31;
    int t = threadIdx.x;
    int row = t >> 2, dseg = (t & 3) << 4;

    float acc[16] = {};
    float lsum = 0.f;
#pragma unroll
    for (int jc = 0; jc < 2; ++jc) {
        const float* Op = Opart + ((size_t)(blk * 2 + jc)) * 4096 + (size_t)row * 64 + dseg;
#pragma unroll
        for (int u = 0; u < 4; ++u) {
            float4 v = *(const float4*)&Op[u * 4];
            acc[u * 4 + 0] += v.x; acc[u * 4 + 1] += v.y;
            acc[u * 4 + 2] += v.z; acc[u * 4 + 3] += v.w;
        }
        lsum += Lpart[(blk * 2 + jc) * 64 + row];
    }
    float inv = 1.0f / lsum;
    int b = bh >> 3, h = bh & 7, tok = it * 64 + row;
    size_t base = ((size_t)b * 2048 + tok) * 512 + h * 64 + dseg;
    bf16x8 oh0, oh1, ol0, ol1;
#pragma unroll
    for (int u = 0; u < 8; ++u) {
        float v0 = acc[u] * inv, v1 = acc[8 + u] * inv;
        bf16 h0 = (bf16)v0, h1 = (bf16)v1;
        oh0[u] = h0; ol0[u] = (bf16)(v0 - (float)h0);
        oh1[u] = h1; ol1[u] = (bf16)(v1 - (float)h1);
    }
    *(bf16x8*)&Oh[base] = oh0;
    *(bf16x8*)&Oh[base + 8] = oh1;
    *(bf16x8*)&Ol[base] = ol0;
    *(bf16x8*)&Ol[base + 8] = ol1;
}

// ---------------- output projection, LDS-staged split-bf16 (R3-exact) --------------
__global__ __launch_bounds__(256) void gemm_out(
    const bf16* __restrict__ Ah, const bf16* __restrict__ Al,
    const bf16* __restrict__ Wh, const bf16* __restrict__ Wl,
    float* __restrict__ C)
{
    __shared__ bf16 AhT[4096], AlT[4096], WhT[4096], WlT[4096];
    int bid = blockIdx.x;
    int m0b = bid & 63, n0 = bid >> 6;
    int t = threadIdx.x, wave = t >> 6, lane = t & 63, l = lane & 15, quad = lane >> 4;
    int m0 = m0b * 64 + wave * 16;
    int nb = n0 * 64;
    f32x4 acc[4] = {};
    for (int k0 = 0; k0 < 512; k0 += 64) {
        __syncthreads();
        stage_async(AhT, Ah + (size_t)m0b * 64 * 512 + k0, 512, t);
        stage_async(AlT, Al + (size_t)m0b * 64 * 512 + k0, 512, t);
        stage_async(WhT, Wh + (size_t)nb * 512 + k0, 512, t);
        stage_async(WlT, Wl + (size_t)nb * 512 + k0, 512, t);
        __syncthreads();
        bf16x8 ah0 = frag(AhT, wave * 16 + l, quad);
        bf16x8 ah1 = frag(AhT, wave * 16 + l, 4 + quad);
        bf16x8 al0 = frag(AlT, wave * 16 + l, quad);
        bf16x8 al1 = frag(AlT, wave * 16 + l, 4 + quad);
#pragma unroll
        for (int nc = 0; nc < 4; ++nc) {
            bf16x8 bh0 = frag(WhT, nc * 16 + l, quad);
            bf16x8 bh1 = frag(WhT, nc * 16 + l, 4 + quad);
            bf16x8 bl0 = frag(WlT, nc * 16 + l, quad);
            bf16x8 bl1 = frag(WlT, nc * 16 + l, 4 + quad);
            acc[nc] = MFMA(ah0, bh0, acc[nc]);
            acc[nc] = MFMA(ah1, bh1, acc[nc]);
            acc[nc] = MFMA(ah0, bl0, acc[nc]);
            acc[nc] = MFMA(ah1, bl1, acc[nc]);
            acc[nc] = MFMA(al0, bh0, acc[nc]);
            acc[nc] = MFMA(al1, bh1, acc[nc]);
        }
    }
#pragma unroll
    for (int nc = 0; nc < 4; ++nc)
#pragma unroll
        for (int r = 0; r < 4; ++r)
            C[(size_t)(m0 + quad * 4 + r) * 512 + nb + nc * 16 + l] = acc[nc][r];
}

extern "C" void kernel_launch(void* const* d_in, const int* in_sizes, int n_in,
                              void* d_out, int out_size, void* d_ws, size_t ws_size,
                              hipStream_t stream) {
    const float* x = (const float*)d_in[0];
    const float* Wq = (const float*)d_in[1];
    const float* Wk = (const float*)d_in[2];
    const float* Wv = (const float*)d_in[3];
    const float* Wo = (const float*)d_in[4];
    const int* seqm = (const int*)d_in[5];
    const int* spm = (const int*)d_in[6];
    float* out = (float*)d_out;

    const size_t E = 2097152;            // 2*2048*512
    bf16* xb = (bf16*)d_ws;
    bf16* Wb = xb + E;
    bf16* Woh = Wb + 786432;
    bf16* Wol = Woh + 262144;
    bf16* Qg = Wol + 262144;
    bf16* Kg = Qg + E;
    bf16* Vtg = Kg + E;                  // [bh][64][2048]
    bf16* Ohb = Vtg + E;
    bf16* Olb = Ohb + E;
    unsigned* pseq = (unsigned*)(Olb + E);
    unsigned* psp = pseq + 262144;
    float* Opart = (float*)(psp + 262144);       // 1024 x 4096 fp32 = 16 MB
    float* Lpart = Opart + (size_t)1024 * 4096;  // 0.25 MB

    hipLaunchKernelGGL(prep, dim3(3584), dim3(256), 0, stream,
                       seqm, spm, x, Wq, Wk, Wv, Wo, pseq, psp, xb, Wb, Woh, Wol);
    hipLaunchKernelGGL(gemm_qkv, dim3(768), dim3(256), 0, stream, xb, Wb, Qg, Kg, Vtg);
    hipLaunchKernelGGL(attn_kernel, dim3(1024), dim3(256), 0, stream,
                       Qg, Kg, Vtg, pseq, psp, Opart, Lpart);
    hipLaunchKernelGGL(attn_combine, dim3(512), dim3(256), 0, stream, Opart, Lpart, Ohb, Olb);
    hipLaunchKernelGGL(gemm_out, dim3(512), dim3(256), 0, stream, Ohb, Olb, Woh, Wol, out);
}

// Round 11
// 181.115 us; speedup vs baseline: 1.6394x; 1.6394x over previous
//
#include <hip/hip_runtime.h>
#include <math.h>

typedef __bf16 bf16;
typedef __bf16 bf16x4 __attribute__((ext_vector_type(4)));
typedef __bf16 bf16x8 __attribute__((ext_vector_type(8)));
typedef float f32x4 __attribute__((ext_vector_type(4)));

#define MFMA(a, b, c) __builtin_amdgcn_mfma_f32_16x16x32_bf16(a, b, c, 0, 0, 0)
#define LOG2E 1.44269504088896340736f

// XOR-swizzled 64x64 bf16 tile (8 KB): elem (row, chunk8) at row*64 + ((ch^(row&7))*8).
// Staged via global_load_lds width=16 — linear LDS dest (wave-uniform base + lane*16),
// inverse-swizzled global source (rule #21: XOR involution -> frag() reads unchanged).
__device__ __forceinline__ void stage_async(bf16* __restrict__ T, const bf16* __restrict__ src,
                                            int rs, int t) {
#pragma unroll
    for (int i = 0; i < 2; ++i) {
        int u = i * 256 + t;                 // 16B chunk index in [0,512)
        int row = u >> 3, ch = u & 7;
        const bf16* g = src + (size_t)row * rs + ((ch ^ (row & 7)) << 3);
        bf16* lp = T + (size_t)(i * 256 + (t & 192)) * 8;   // wave-uniform base; HW adds lane*16
        __builtin_amdgcn_global_load_lds((__attribute__((address_space(1))) void*)g,
                                         (__attribute__((address_space(3))) void*)lp,
                                         16, 0, 0);
    }
}
__device__ __forceinline__ bf16x8 frag(const bf16* __restrict__ T, int row, int ch) {
    return *(const bf16x8*)&T[row * 64 + ((ch ^ (row & 7)) << 3)];
}
// P tile [16 rows][64 cols] with 16B-slot XOR swizzle; <=2-way conflicts (free).
__device__ __forceinline__ int pidx(int l, int k) {
    return l * 64 + ((((k >> 3) ^ (l & 7))) << 3) + (k & 7);
}

// ---------------- fused preprocessing (vectorized mask packing) --------------------
__global__ __launch_bounds__(256) void prep(
    const int* __restrict__ seqm, const int* __restrict__ spm,
    const float* __restrict__ x,
    const float* __restrict__ Wq, const float* __restrict__ Wk,
    const float* __restrict__ Wv, const float* __restrict__ Wo,
    unsigned* __restrict__ pseq, unsigned* __restrict__ psp,
    bf16* __restrict__ xb, bf16* __restrict__ Wb,
    bf16* __restrict__ Woh, bf16* __restrict__ Wol)
{
    int bid = blockIdx.x, t = threadIdx.x;
    if (bid < 2048) {
        int wave = t >> 6, lane = t & 63;
        int row = bid * 4 + wave;
        const int* src = (row < 4096) ? (seqm + (size_t)row * 2048)
                                      : (spm + (size_t)(row - 4096) * 2048);
        unsigned* dst = (row < 4096) ? (pseq + (size_t)row * 64)
                                     : (psp + (size_t)(row - 4096) * 64);
        const int4* s4 = (const int4*)src;
        unsigned bits = 0;
#pragma unroll
        for (int c = 0; c < 8; ++c) {
            int4 v = s4[lane * 8 + c];
            bits |= (v.x != 0 ? 1u : 0u) << (c * 4);
            bits |= (v.y != 0 ? 1u : 0u) << (c * 4 + 1);
            bits |= (v.z != 0 ? 1u : 0u) << (c * 4 + 2);
            bits |= (v.w != 0 ? 1u : 0u) << (c * 4 + 3);
        }
        dst[lane] = bits;
    } else if (bid < 3072) {
        int i = ((bid - 2048) * 256 + t) * 8;
        float4 a = *(const float4*)&x[i];
        float4 c = *(const float4*)&x[i + 4];
        float v[8] = {a.x, a.y, a.z, a.w, c.x, c.y, c.z, c.w};
        bf16x8 o;
#pragma unroll
        for (int u = 0; u < 8; ++u) o[u] = (bf16)v[u];
        *(bf16x8*)&xb[i] = o;
    } else {
        int zb = bid - 3072;
        int z = zb >> 7;
        int i = ((zb & 127) * 256 + t) * 8;
        const float* src = (z == 0) ? Wq : (z == 1) ? Wk : (z == 2) ? Wv : Wo;
        float4 a = *(const float4*)&src[i];
        float4 c = *(const float4*)&src[i + 4];
        float v[8] = {a.x, a.y, a.z, a.w, c.x, c.y, c.z, c.w};
        if (z < 3) {
            bf16x8 o;
#pragma unroll
            for (int u = 0; u < 8; ++u) o[u] = (bf16)v[u];
            *(bf16x8*)&Wb[(size_t)z * 262144 + i] = o;
        } else {
            bf16x8 oh, ol;
#pragma unroll
            for (int u = 0; u < 8; ++u) {
                bf16 hi = (bf16)v[u];
                oh[u] = hi;
                ol[u] = (bf16)(v[u] - (float)hi);
            }
            *(bf16x8*)&Woh[i] = oh;
            *(bf16x8*)&Wol[i] = ol;
        }
    }
}

// ---------------- fused QKV projection (R5-proven: single-barrier dbuf) ------------
__global__ __launch_bounds__(256) void gemm_qkv(
    const bf16* __restrict__ A, const bf16* __restrict__ Wb,
    bf16* __restrict__ Qg, bf16* __restrict__ Kg, bf16* __restrict__ Vt)
{
    __shared__ bf16 SM[24576];           // set s at SM + s*12288 (tiles +0,+4096,+8192)
    bf16* Lt = SM;                       // epilogue scratch, post-loop only
    int bid = blockIdx.x;
    int m0b = bid & 63;
    int rest = bid >> 6;
    int np = rest & 3, z = rest >> 2;
    const bf16* W = Wb + (size_t)z * 262144;
    float scale = (z == 0) ? (0.125f * LOG2E) : 1.0f;

    int t = threadIdx.x, wave = t >> 6, lane = t & 63, l = lane & 15, quad = lane >> 4;
    int m0 = m0b * 64 + wave * 16;
    int nb = np * 128;
    const bf16* Abase = A + (size_t)m0b * 64 * 512;
    const bf16* W0base = W + (size_t)nb * 512;
    const bf16* W1base = W + (size_t)(nb + 64) * 512;

    stage_async(SM, Abase, 512, t);
    stage_async(SM + 4096, W0base, 512, t);
    stage_async(SM + 8192, W1base, 512, t);

    f32x4 acc[8] = {};
    for (int ks = 0; ks < 8; ++ks) {
        bf16* set = SM + (ks & 1) * 12288;
        __syncthreads();                 // drains stage(ks) vmcnt + prior set reads
        if (ks < 7) {
            int k0 = (ks + 1) * 64;
            bf16* nset = SM + ((ks + 1) & 1) * 12288;
            stage_async(nset, Abase + k0, 512, t);
            stage_async(nset + 4096, W0base + k0, 512, t);
            stage_async(nset + 8192, W1base + k0, 512, t);
        }
        bf16x8 a0 = frag(set, wave * 16 + l, quad);
        bf16x8 a1 = frag(set, wave * 16 + l, 4 + quad);
#pragma unroll
        for (int nc = 0; nc < 4; ++nc) {
            bf16x8 b0 = frag(set + 4096, nc * 16 + l, quad);
            bf16x8 b1 = frag(set + 4096, nc * 16 + l, 4 + quad);
            acc[nc] = MFMA(a0, b0, acc[nc]);
            acc[nc] = MFMA(a1, b1, acc[nc]);
        }
#pragma unroll
        for (int nc = 0; nc < 4; ++nc) {
            bf16x8 b0 = frag(set + 8192, nc * 16 + l, quad);
            bf16x8 b1 = frag(set + 8192, nc * 16 + l, 4 + quad);
            acc[4 + nc] = MFMA(a0, b0, acc[4 + nc]);
            acc[4 + nc] = MFMA(a1, b1, acc[4 + nc]);
        }
    }
    if (z < 2) {
        bf16* out = (z == 0) ? Qg : Kg;
#pragma unroll
        for (int nc = 0; nc < 8; ++nc) {
#pragma unroll
            for (int r = 0; r < 4; ++r) {
                int m = m0 + quad * 4 + r;
                int feat = nb + nc * 16 + l;
                int b = m >> 11, tok = m & 2047, h = feat >> 6, d = feat & 63;
                out[(((size_t)(b * 8 + h)) * 2048 + tok) * 64 + d] = (bf16)(acc[nc][r] * scale);
            }
        }
    } else {
#pragma unroll
        for (int hh = 0; hh < 2; ++hh) {
            __syncthreads();
#pragma unroll
            for (int nc = 0; nc < 4; ++nc)
#pragma unroll
                for (int r = 0; r < 4; ++r)
                    Lt[(nc * 16 + l) * 72 + wave * 16 + quad * 4 + r] = (bf16)acc[hh * 4 + nc][r];
            __syncthreads();
            int d = t >> 2, seg = t & 3;
            int tok0 = m0b * 64;
            int b = tok0 >> 11, h = np * 2 + hh;
            bf16x8 o0, o1;
#pragma unroll
            for (int i = 0; i < 8; ++i) { o0[i] = Lt[d * 72 + seg * 16 + i]; o1[i] = Lt[d * 72 + seg * 16 + 8 + i]; }
            size_t base = ((size_t)(b * 8 + h) * 64 + d) * 2048 + (tok0 & 2047) + seg * 16;
            *(bf16x8*)&Vt[base] = o0;
            *(bf16x8*)&Vt[base + 8] = o1;
        }
    }
}

// ---------------- flash attention (R11: K-single / V-double, 32KB LDS) -------------
// grid 2048 = jc(2b) | it(5b) | bh(4b); 4 waves; LDS = KT 8KB + VT dbuf 16KB + P 8KB
// = 32KB -> 5 blocks/CU (LDS-limited; no launch_bounds min-waves pin — R8 lesson).
// Keeps R6's pipeline property (PV(j-1) overlapped with QK(j), pa carried 8 regs)
// WITHOUT loop-carried V regs (the R9 spill cause): PV reads V frags from LDS
// in-iteration. Per iter jj: [barrier A crossed: K(jj),V(jj) staged] QK(jj) from KT;
// PV(jj-1) from VT[(jj-1)&1]; barrier B (closes KT + VT[(jj-1)&1] reads);
// stage K(jj+1)->KT, V(jj+1)->VT[(jj+1)&1] (= (jj-1)&1, safe after B);
// softmax(jj)->pa (hides stage latency); barrier A.
__global__ __launch_bounds__(256) void attn_kernel(
    const bf16* __restrict__ Qg, const bf16* __restrict__ Kg, const bf16* __restrict__ Vt,
    const unsigned* __restrict__ pseq, const unsigned* __restrict__ psp,
    float* __restrict__ Opart, float* __restrict__ Lpart)
{
    __shared__ bf16 KT[4096], VT[2][4096];
    __shared__ bf16 P[4][1024];
    int bid = blockIdx.x;
    int bh = bid & 15;                       // XCD = bid%8 -> K/V L2-resident
    int it = (bid >> 4) & 31;
    int jc = bid >> 9;                       // 0..3
    int i0 = it * 64;
    int b = bh >> 3, par = bh & 1;
    int t = threadIdx.x, rg = t >> 6, lane = t & 63, l = lane & 15, quad = lane >> 4;

    const bf16* Qp = Qg + ((size_t)bh * 2048 + i0 + rg * 16 + l) * 64;
    bf16x8 qf0 = *(const bf16x8*)&Qp[quad * 8];
    bf16x8 qf1 = *(const bf16x8*)&Qp[32 + quad * 8];

    bf16x8 ones;
#pragma unroll
    for (int i = 0; i < 8; ++i) ones[i] = (bf16)1.0f;
    const f32x4 fz = {0.f, 0.f, 0.f, 0.f};

    f32x4 o_acc[4] = {}, l_acc = {};

    int qrow = i0 + rg * 16 + l;
    const unsigned* seqp = pseq + (size_t)b * 131072 + (size_t)qrow * 64;
    const unsigned* sppp = psp + (size_t)par * 131072 + (size_t)qrow * 64;
    const bf16* Kbase = Kg + (size_t)bh * 2048 * 64;
    const bf16* Vbase = Vt + (size_t)bh * 64 * 2048;
    bf16* Pb = P[rg];

    const int NT = 8;
    int jlo = jc * 512;

    stage_async(KT, Kbase + (size_t)jlo * 64, 64, t);
    stage_async(VT[0], Vbase + jlo, 2048, t);
    __syncthreads();                         // barrier A for jj=0: stage(0) drained

    bf16x8 pa0 = {}, pa1 = {};

    for (int jj = 0; jj < NT; ++jj) {
        int j0 = jlo + jj * 64;
        uint2 mseq = *(const uint2*)&seqp[j0 >> 5];
        uint2 msp = *(const uint2*)&sppp[j0 >> 5];
        unsigned w0 = mseq.x & msp.x, w1 = mseq.y & msp.y;

        // QK(jj) from KT + PV(jj-1) from VT[(jj-1)&1]; both MFMA streams interleave
        f32x4 s[4];
        __builtin_amdgcn_s_setprio(1);
#pragma unroll
        for (int nc = 0; nc < 4; ++nc) {
            bf16x8 k0f = frag(KT, nc * 16 + l, quad);
            bf16x8 k1f = frag(KT, nc * 16 + l, 4 + quad);
            s[nc] = MFMA(k0f, qf0, fz);
            s[nc] = MFMA(k1f, qf1, s[nc]);
        }
        if (jj > 0) {
            const bf16* Vp = VT[(jj - 1) & 1];
            l_acc = MFMA(pa0, ones, l_acc);
            l_acc = MFMA(pa1, ones, l_acc);
#pragma unroll
            for (int dc = 0; dc < 4; ++dc) {
                bf16x8 vb0 = frag(Vp, dc * 16 + l, quad);
                bf16x8 vb1 = frag(Vp, dc * 16 + l, 4 + quad);
                o_acc[dc] = MFMA(pa0, vb0, o_acc[dc]);
                o_acc[dc] = MFMA(pa1, vb1, o_acc[dc]);
            }
        }
        __builtin_amdgcn_s_setprio(0);

        __syncthreads();                     // barrier B: KT + VT[(jj-1)&1] reads done

        if (jj + 1 < NT) {
            stage_async(KT, Kbase + (size_t)(j0 + 64) * 64, 64, t);
            stage_async(VT[(jj + 1) & 1], Vbase + (j0 + 64), 2048, t);
        }

        // softmax(jj) -> P -> pa regs (consumed next iteration); hides stage latency
#pragma unroll
        for (int nc = 0; nc < 4; ++nc) {
            unsigned w = (nc < 2) ? w0 : w1;
            int bbase = (nc & 1) * 16 + quad * 4;
            bf16x4 pv;
#pragma unroll
            for (int r = 0; r < 4; ++r) {
                float e = __builtin_amdgcn_exp2f(s[nc][r]);
                pv[r] = (bf16)(((w >> (bbase + r)) & 1u) ? e : 0.f);
            }
            *(bf16x4*)&Pb[pidx(l, nc * 16 + quad * 4)] = pv;
        }
        pa0 = *(const bf16x8*)&Pb[pidx(l, quad * 8)];
        pa1 = *(const bf16x8*)&Pb[pidx(l, 32 + quad * 8)];

        __syncthreads();                     // barrier A: drains stage(jj+1)
    }

    // epilogue: PV(NT-1); VT[(NT-1)&1] was drained and never restaged
    {
        const bf16* Vp = VT[(NT - 1) & 1];
        __builtin_amdgcn_s_setprio(1);
        l_acc = MFMA(pa0, ones, l_acc);
        l_acc = MFMA(pa1, ones, l_acc);
#pragma unroll
        for (int dc = 0; dc < 4; ++dc) {
            bf16x8 vb0 = frag(Vp, dc * 16 + l, quad);
            bf16x8 vb1 = frag(Vp, dc * 16 + l, 4 + quad);
            o_acc[dc] = MFMA(pa0, vb0, o_acc[dc]);
            o_acc[dc] = MFMA(pa1, vb1, o_acc[dc]);
        }
        __builtin_amdgcn_s_setprio(0);
    }

    size_t pb = ((size_t)((bh * 32 + it) * 4 + jc)) * 4096;
#pragma unroll
    for (int dc = 0; dc < 4; ++dc)
#pragma unroll
        for (int r = 0; r < 4; ++r)
            Opart[pb + (size_t)(rg * 16 + quad * 4 + r) * 64 + dc * 16 + l] = o_acc[dc][r];
    if (l == 0) {
#pragma unroll
        for (int r = 0; r < 4; ++r)
            Lpart[((bh * 32 + it) * 4 + jc) * 64 + rg * 16 + quad * 4 + r] = l_acc[r];
    }
}

// ---------------- combine partials -> normalized split-bf16 O (jc=4, R2-proven) ----
__global__ __launch_bounds__(256) void attn_combine(
    const float* __restrict__ Opart, const float* __restrict__ Lpart,
    bf16* __restrict__ Oh, bf16* __restrict__ Ol)
{
    int blk = blockIdx.x;
    int bh = blk >> 5, it = blk & 31;
    int t = threadIdx.x;
    int row = t >> 2, dseg = (t & 3) << 4;

    float acc[16] = {};
    float lsum = 0.f;
#pragma unroll
    for (int jc = 0; jc < 4; ++jc) {
        const float* Op = Opart + ((size_t)(blk * 4 + jc)) * 4096 + (size_t)row * 64 + dseg;
#pragma unroll
        for (int u = 0; u < 4; ++u) {
            float4 v = *(const float4*)&Op[u * 4];
            acc[u * 4 + 0] += v.x; acc[u * 4 + 1] += v.y;
            acc[u * 4 + 2] += v.z; acc[u * 4 + 3] += v.w;
        }
        lsum += Lpart[(blk * 4 + jc) * 64 + row];
    }
    float inv = 1.0f / lsum;
    int b = bh >> 3, h = bh & 7, tok = it * 64 + row;
    size_t base = ((size_t)b * 2048 + tok) * 512 + h * 64 + dseg;
    bf16x8 oh0, oh1, ol0, ol1;
#pragma unroll
    for (int u = 0; u < 8; ++u) {
        float v0 = acc[u] * inv, v1 = acc[8 + u] * inv;
        bf16 h0 = (bf16)v0, h1 = (bf16)v1;
        oh0[u] = h0; ol0[u] = (bf16)(v0 - (float)h0);
        oh1[u] = h1; ol1[u] = (bf16)(v1 - (float)h1);
    }
    *(bf16x8*)&Oh[base] = oh0;
    *(bf16x8*)&Oh[base + 8] = oh1;
    *(bf16x8*)&Ol[base] = ol0;
    *(bf16x8*)&Ol[base + 8] = ol1;
}

// ---------------- output projection, LDS-staged split-bf16 (R3-exact) --------------
__global__ __launch_bounds__(256) void gemm_out(
    const bf16* __restrict__ Ah, const bf16* __restrict__ Al,
    const bf16* __restrict__ Wh, const bf16* __restrict__ Wl,
    float* __restrict__ C)
{
    __shared__ bf16 AhT[4096], AlT[4096], WhT[4096], WlT[4096];
    int bid = blockIdx.x;
    int m0b = bid & 63, n0 = bid >> 6;
    int t = threadIdx.x, wave = t >> 6, lane = t & 63, l = lane & 15, quad = lane >> 4;
    int m0 = m0b * 64 + wave * 16;
    int nb = n0 * 64;
    f32x4 acc[4] = {};
    for (int k0 = 0; k0 < 512; k0 += 64) {
        __syncthreads();
        stage_async(AhT, Ah + (size_t)m0b * 64 * 512 + k0, 512, t);
        stage_async(AlT, Al + (size_t)m0b * 64 * 512 + k0, 512, t);
        stage_async(WhT, Wh + (size_t)nb * 512 + k0, 512, t);
        stage_async(WlT, Wl + (size_t)nb * 512 + k0, 512, t);
        __syncthreads();
        bf16x8 ah0 = frag(AhT, wave * 16 + l, quad);
        bf16x8 ah1 = frag(AhT, wave * 16 + l, 4 + quad);
        bf16x8 al0 = frag(AlT, wave * 16 + l, quad);
        bf16x8 al1 = frag(AlT, wave * 16 + l, 4 + quad);
#pragma unroll
        for (int nc = 0; nc < 4; ++nc) {
            bf16x8 bh0 = frag(WhT, nc * 16 + l, quad);
            bf16x8 bh1 = frag(WhT, nc * 16 + l, 4 + quad);
            bf16x8 bl0 = frag(WlT, nc * 16 + l, quad);
            bf16x8 bl1 = frag(WlT, nc * 16 + l, 4 + quad);
            acc[nc] = MFMA(ah0, bh0, acc[nc]);
            acc[nc] = MFMA(ah1, bh1, acc[nc]);
            acc[nc] = MFMA(ah0, bl0, acc[nc]);
            acc[nc] = MFMA(ah1, bl1, acc[nc]);
            acc[nc] = MFMA(al0, bh0, acc[nc]);
            acc[nc] = MFMA(al1, bh1, acc[nc]);
        }
    }
#pragma unroll
    for (int nc = 0; nc < 4; ++nc)
#pragma unroll
        for (int r = 0; r < 4; ++r)
            C[(size_t)(m0 + quad * 4 + r) * 512 + nb + nc * 16 + l] = acc[nc][r];
}

extern "C" void kernel_launch(void* const* d_in, const int* in_sizes, int n_in,
                              void* d_out, int out_size, void* d_ws, size_t ws_size,
                              hipStream_t stream) {
    const float* x = (const float*)d_in[0];
    const float* Wq = (const float*)d_in[1];
    const float* Wk = (const float*)d_in[2];
    const float* Wv = (const float*)d_in[3];
    const float* Wo = (const float*)d_in[4];
    const int* seqm = (const int*)d_in[5];
    const int* spm = (const int*)d_in[6];
    float* out = (float*)d_out;

    const size_t E = 2097152;            // 2*2048*512
    bf16* xb = (bf16*)d_ws;
    bf16* Wb = xb + E;
    bf16* Woh = Wb + 786432;
    bf16* Wol = Woh + 262144;
    bf16* Qg = Wol + 262144;
    bf16* Kg = Qg + E;
    bf16* Vtg = Kg + E;                  // [bh][64][2048]
    bf16* Ohb = Vtg + E;
    bf16* Olb = Ohb + E;
    unsigned* pseq = (unsigned*)(Olb + E);
    unsigned* psp = pseq + 262144;
    float* Opart = (float*)(psp + 262144);       // 2048 x 4096 fp32 = 32 MB
    float* Lpart = Opart + (size_t)2048 * 4096;  // 0.5 MB

    hipLaunchKernelGGL(prep, dim3(3584), dim3(256), 0, stream,
                       seqm, spm, x, Wq, Wk, Wv, Wo, pseq, psp, xb, Wb, Woh, Wol);
    hipLaunchKernelGGL(gemm_qkv, dim3(768), dim3(256), 0, stream, xb, Wb, Qg, Kg, Vtg);
    hipLaunchKernelGGL(attn_kernel, dim3(2048), dim3(256), 0, stream,
                       Qg, Kg, Vtg, pseq, psp, Opart, Lpart);
    hipLaunchKernelGGL(attn_combine, dim3(512), dim3(256), 0, stream, Opart, Lpart, Ohb, Olb);
    hipLaunchKernelGGL(gemm_out, dim3(512), dim3(256), 0, stream, Ohb, Olb, Woh, Wol, out);
}

// Round 12
// 174.221 us; speedup vs baseline: 1.7042x; 1.0396x over previous
//
#include <hip/hip_runtime.h>
#include <math.h>

typedef __bf16 bf16;
typedef __bf16 bf16x4 __attribute__((ext_vector_type(4)));
typedef __bf16 bf16x8 __attribute__((ext_vector_type(8)));
typedef float f32x4 __attribute__((ext_vector_type(4)));

#define MFMA(a, b, c) __builtin_amdgcn_mfma_f32_16x16x32_bf16(a, b, c, 0, 0, 0)
#define LOG2E 1.44269504088896340736f

// XOR-swizzled 64x64 bf16 tile (8 KB): elem (row, chunk8) at row*64 + ((ch^(row&7))*8).
// Staged via global_load_lds width=16 — linear LDS dest (wave-uniform base + lane*16),
// inverse-swizzled global source (rule #21: XOR involution -> frag() reads unchanged).
__device__ __forceinline__ void stage_async(bf16* __restrict__ T, const bf16* __restrict__ src,
                                            int rs, int t) {
#pragma unroll
    for (int i = 0; i < 2; ++i) {
        int u = i * 256 + t;                 // 16B chunk index in [0,512)
        int row = u >> 3, ch = u & 7;
        const bf16* g = src + (size_t)row * rs + ((ch ^ (row & 7)) << 3);
        bf16* lp = T + (size_t)(i * 256 + (t & 192)) * 8;   // wave-uniform base; HW adds lane*16
        __builtin_amdgcn_global_load_lds((__attribute__((address_space(1))) void*)g,
                                         (__attribute__((address_space(3))) void*)lp,
                                         16, 0, 0);
    }
}
__device__ __forceinline__ bf16x8 frag(const bf16* __restrict__ T, int row, int ch) {
    return *(const bf16x8*)&T[row * 64 + ((ch ^ (row & 7)) << 3)];
}
// P tile [16 rows][64 cols] with 16B-slot XOR swizzle; <=2-way conflicts (free).
__device__ __forceinline__ int pidx(int l, int k) {
    return l * 64 + ((((k >> 3) ^ (l & 7))) << 3) + (k & 7);
}

// ---------------- fused preprocessing (vectorized mask packing) --------------------
__global__ __launch_bounds__(256) void prep(
    const int* __restrict__ seqm, const int* __restrict__ spm,
    const float* __restrict__ x,
    const float* __restrict__ Wq, const float* __restrict__ Wk,
    const float* __restrict__ Wv, const float* __restrict__ Wo,
    unsigned* __restrict__ pseq, unsigned* __restrict__ psp,
    bf16* __restrict__ xb, bf16* __restrict__ Wb,
    bf16* __restrict__ Woh, bf16* __restrict__ Wol)
{
    int bid = blockIdx.x, t = threadIdx.x;
    if (bid < 2048) {
        int wave = t >> 6, lane = t & 63;
        int row = bid * 4 + wave;
        const int* src = (row < 4096) ? (seqm + (size_t)row * 2048)
                                      : (spm + (size_t)(row - 4096) * 2048);
        unsigned* dst = (row < 4096) ? (pseq + (size_t)row * 64)
                                     : (psp + (size_t)(row - 4096) * 64);
        const int4* s4 = (const int4*)src;
        unsigned bits = 0;
#pragma unroll
        for (int c = 0; c < 8; ++c) {
            int4 v = s4[lane * 8 + c];
            bits |= (v.x != 0 ? 1u : 0u) << (c * 4);
            bits |= (v.y != 0 ? 1u : 0u) << (c * 4 + 1);
            bits |= (v.z != 0 ? 1u : 0u) << (c * 4 + 2);
            bits |= (v.w != 0 ? 1u : 0u) << (c * 4 + 3);
        }
        dst[lane] = bits;
    } else if (bid < 3072) {
        int i = ((bid - 2048) * 256 + t) * 8;
        float4 a = *(const float4*)&x[i];
        float4 c = *(const float4*)&x[i + 4];
        float v[8] = {a.x, a.y, a.z, a.w, c.x, c.y, c.z, c.w};
        bf16x8 o;
#pragma unroll
        for (int u = 0; u < 8; ++u) o[u] = (bf16)v[u];
        *(bf16x8*)&xb[i] = o;
    } else {
        int zb = bid - 3072;
        int z = zb >> 7;
        int i = ((zb & 127) * 256 + t) * 8;
        const float* src = (z == 0) ? Wq : (z == 1) ? Wk : (z == 2) ? Wv : Wo;
        float4 a = *(const float4*)&src[i];
        float4 c = *(const float4*)&src[i + 4];
        float v[8] = {a.x, a.y, a.z, a.w, c.x, c.y, c.z, c.w};
        if (z < 3) {
            bf16x8 o;
#pragma unroll
            for (int u = 0; u < 8; ++u) o[u] = (bf16)v[u];
            *(bf16x8*)&Wb[(size_t)z * 262144 + i] = o;
        } else {
            bf16x8 oh, ol;
#pragma unroll
            for (int u = 0; u < 8; ++u) {
                bf16 hi = (bf16)v[u];
                oh[u] = hi;
                ol[u] = (bf16)(v[u] - (float)hi);
            }
            *(bf16x8*)&Woh[i] = oh;
            *(bf16x8*)&Wol[i] = ol;
        }
    }
}

// ---------------- fused QKV projection (R5-proven: single-barrier dbuf) ------------
__global__ __launch_bounds__(256) void gemm_qkv(
    const bf16* __restrict__ A, const bf16* __restrict__ Wb,
    bf16* __restrict__ Qg, bf16* __restrict__ Kg, bf16* __restrict__ Vt)
{
    __shared__ bf16 SM[24576];           // set s at SM + s*12288 (tiles +0,+4096,+8192)
    bf16* Lt = SM;                       // epilogue scratch, post-loop only
    int bid = blockIdx.x;
    int m0b = bid & 63;
    int rest = bid >> 6;
    int np = rest & 3, z = rest >> 2;
    const bf16* W = Wb + (size_t)z * 262144;
    float scale = (z == 0) ? (0.125f * LOG2E) : 1.0f;

    int t = threadIdx.x, wave = t >> 6, lane = t & 63, l = lane & 15, quad = lane >> 4;
    int m0 = m0b * 64 + wave * 16;
    int nb = np * 128;
    const bf16* Abase = A + (size_t)m0b * 64 * 512;
    const bf16* W0base = W + (size_t)nb * 512;
    const bf16* W1base = W + (size_t)(nb + 64) * 512;

    stage_async(SM, Abase, 512, t);
    stage_async(SM + 4096, W0base, 512, t);
    stage_async(SM + 8192, W1base, 512, t);

    f32x4 acc[8] = {};
    for (int ks = 0; ks < 8; ++ks) {
        bf16* set = SM + (ks & 1) * 12288;
        __syncthreads();                 // drains stage(ks) vmcnt + prior set reads
        if (ks < 7) {
            int k0 = (ks + 1) * 64;
            bf16* nset = SM + ((ks + 1) & 1) * 12288;
            stage_async(nset, Abase + k0, 512, t);
            stage_async(nset + 4096, W0base + k0, 512, t);
            stage_async(nset + 8192, W1base + k0, 512, t);
        }
        bf16x8 a0 = frag(set, wave * 16 + l, quad);
        bf16x8 a1 = frag(set, wave * 16 + l, 4 + quad);
#pragma unroll
        for (int nc = 0; nc < 4; ++nc) {
            bf16x8 b0 = frag(set + 4096, nc * 16 + l, quad);
            bf16x8 b1 = frag(set + 4096, nc * 16 + l, 4 + quad);
            acc[nc] = MFMA(a0, b0, acc[nc]);
            acc[nc] = MFMA(a1, b1, acc[nc]);
        }
#pragma unroll
        for (int nc = 0; nc < 4; ++nc) {
            bf16x8 b0 = frag(set + 8192, nc * 16 + l, quad);
            bf16x8 b1 = frag(set + 8192, nc * 16 + l, 4 + quad);
            acc[4 + nc] = MFMA(a0, b0, acc[4 + nc]);
            acc[4 + nc] = MFMA(a1, b1, acc[4 + nc]);
        }
    }
    if (z < 2) {
        bf16* out = (z == 0) ? Qg : Kg;
#pragma unroll
        for (int nc = 0; nc < 8; ++nc) {
#pragma unroll
            for (int r = 0; r < 4; ++r) {
                int m = m0 + quad * 4 + r;
                int feat = nb + nc * 16 + l;
                int b = m >> 11, tok = m & 2047, h = feat >> 6, d = feat & 63;
                out[(((size_t)(b * 8 + h)) * 2048 + tok) * 64 + d] = (bf16)(acc[nc][r] * scale);
            }
        }
    } else {
#pragma unroll
        for (int hh = 0; hh < 2; ++hh) {
            __syncthreads();
#pragma unroll
            for (int nc = 0; nc < 4; ++nc)
#pragma unroll
                for (int r = 0; r < 4; ++r)
                    Lt[(nc * 16 + l) * 72 + wave * 16 + quad * 4 + r] = (bf16)acc[hh * 4 + nc][r];
            __syncthreads();
            int d = t >> 2, seg = t & 3;
            int tok0 = m0b * 64;
            int b = tok0 >> 11, h = np * 2 + hh;
            bf16x8 o0, o1;
#pragma unroll
            for (int i = 0; i < 8; ++i) { o0[i] = Lt[d * 72 + seg * 16 + i]; o1[i] = Lt[d * 72 + seg * 16 + 8 + i]; }
            size_t base = ((size_t)(b * 8 + h) * 64 + d) * 2048 + (tok0 & 2047) + seg * 16;
            *(bf16x8*)&Vt[base] = o0;
            *(bf16x8*)&Vt[base + 8] = o1;
        }
    }
}

// ---------------- flash attention (R6-exact: best measured, total 175.2us) ---------
// grid 1024 = jc(1b) | it(5b) | bh(4b); 4 waves; LDS 40KB -> 4 blocks/CU resident.
// PV(j-1) runs concurrently with QK(j)+softmax(j): V(j-1) pre-read to regs before its
// buffer is re-staged (2nd barrier protects cross-wave WAR); P fragments carried in
// regs across iterations. Session plateau: 6 structural variants (R2/R6/R7/R9/R10/
// R11) all land ~41-43us attn — aggregate-issue-bound at 4 waves/SIMD; 5th wave
// unreachable (reg-cap spills, LDS-shrink tail effects). This is the best config.
__global__ __launch_bounds__(256, 4) void attn_kernel(
    const bf16* __restrict__ Qg, const bf16* __restrict__ Kg, const bf16* __restrict__ Vt,
    const unsigned* __restrict__ pseq, const unsigned* __restrict__ psp,
    float* __restrict__ Opart, float* __restrict__ Lpart)
{
    __shared__ bf16 KT[2][4096], VT[2][4096];
    __shared__ bf16 P[4][1024];
    int bid = blockIdx.x;
    int bh = bid & 15;                       // XCD = bid%8 -> K/V L2-resident
    int it = (bid >> 4) & 31;
    int jc = bid >> 9;                       // 0..1
    int i0 = it * 64;
    int b = bh >> 3, par = bh & 1;
    int t = threadIdx.x, rg = t >> 6, lane = t & 63, l = lane & 15, quad = lane >> 4;

    const bf16* Qp = Qg + ((size_t)bh * 2048 + i0 + rg * 16 + l) * 64;
    bf16x8 qf0 = *(const bf16x8*)&Qp[quad * 8];
    bf16x8 qf1 = *(const bf16x8*)&Qp[32 + quad * 8];

    bf16x8 ones;
#pragma unroll
    for (int i = 0; i < 8; ++i) ones[i] = (bf16)1.0f;
    const f32x4 fz = {0.f, 0.f, 0.f, 0.f};

    f32x4 o_acc[4] = {}, l_acc = {};

    int qrow = i0 + rg * 16 + l;
    const unsigned* seqp = pseq + (size_t)b * 131072 + (size_t)qrow * 64;
    const unsigned* sppp = psp + (size_t)par * 131072 + (size_t)qrow * 64;
    const bf16* Kbase = Kg + (size_t)bh * 2048 * 64;
    const bf16* Vbase = Vt + (size_t)bh * 64 * 2048;
    bf16* Pb = P[rg];

    const int NT = 16;
    int jlo = jc * 1024;

    // prologue: stage tile 0; tile 1 issued after tile 0 is consumed-safe
    stage_async(KT[0], Kbase + (size_t)jlo * 64, 64, t);
    stage_async(VT[0], Vbase + jlo, 2048, t);
    bf16x8 pa0, pa1;
    {
        uint2 mseq = *(const uint2*)&seqp[jlo >> 5];
        uint2 msp = *(const uint2*)&sppp[jlo >> 5];
        unsigned w0 = mseq.x & msp.x, w1 = mseq.y & msp.y;
        __syncthreads();                     // K(0),V(0) ready
        stage_async(KT[1], Kbase + (size_t)(jlo + 64) * 64, 64, t);
        stage_async(VT[1], Vbase + (jlo + 64), 2048, t);
        f32x4 s[4];
        __builtin_amdgcn_s_setprio(1);
#pragma unroll
        for (int nc = 0; nc < 4; ++nc) {
            bf16x8 k0f = frag(KT[0], nc * 16 + l, quad);
            bf16x8 k1f = frag(KT[0], nc * 16 + l, 4 + quad);
            s[nc] = MFMA(k0f, qf0, fz);
            s[nc] = MFMA(k1f, qf1, s[nc]);
        }
        __builtin_amdgcn_s_setprio(0);
#pragma unroll
        for (int nc = 0; nc < 4; ++nc) {
            unsigned w = (nc < 2) ? w0 : w1;
            int bbase = (nc & 1) * 16 + quad * 4;
            bf16x4 pv;
#pragma unroll
            for (int r = 0; r < 4; ++r) {
                float e = __builtin_amdgcn_exp2f(s[nc][r]);
                pv[r] = (bf16)(((w >> (bbase + r)) & 1u) ? e : 0.f);
            }
            *(bf16x4*)&Pb[pidx(l, nc * 16 + quad * 4)] = pv;
        }
        pa0 = *(const bf16x8*)&Pb[pidx(l, quad * 8)];
        pa1 = *(const bf16x8*)&Pb[pidx(l, 32 + quad * 8)];
    }

    for (int jj = 1; jj < NT; ++jj) {
        int cur = jj & 1;
        int j0 = jlo + jj * 64;
        uint2 mseq = *(const uint2*)&seqp[j0 >> 5];
        uint2 msp = *(const uint2*)&sppp[j0 >> 5];
        unsigned w0 = mseq.x & msp.x, w1 = mseq.y & msp.y;

        __syncthreads();                     // stage(jj) drained: K(jj),V(jj) ready
        // pre-read V(jj-1) to regs before its buffer is re-staged
        const bf16* Vp = VT[cur ^ 1];
        bf16x8 vr0 = frag(Vp, 0 * 16 + l, quad), vr1 = frag(Vp, 0 * 16 + l, 4 + quad);
        bf16x8 vr2 = frag(Vp, 1 * 16 + l, quad), vr3 = frag(Vp, 1 * 16 + l, 4 + quad);
        bf16x8 vr4 = frag(Vp, 2 * 16 + l, quad), vr5 = frag(Vp, 2 * 16 + l, 4 + quad);
        bf16x8 vr6 = frag(Vp, 3 * 16 + l, quad), vr7 = frag(Vp, 3 * 16 + l, 4 + quad);
        __syncthreads();                     // all waves' V(jj-1) reads complete (WAR)
        if (jj + 1 < NT) {
            stage_async(KT[cur ^ 1], Kbase + (size_t)(j0 + 64) * 64, 64, t);
            stage_async(VT[cur ^ 1], Vbase + (j0 + 64), 2048, t);
        }

        f32x4 s[4];
        __builtin_amdgcn_s_setprio(1);
        // PV(jj-1): pure-register operands, fills MFMA pipe under QK's ds_reads
        l_acc = MFMA(pa0, ones, l_acc);
        l_acc = MFMA(pa1, ones, l_acc);
        o_acc[0] = MFMA(pa0, vr0, o_acc[0]); o_acc[0] = MFMA(pa1, vr1, o_acc[0]);
        o_acc[1] = MFMA(pa0, vr2, o_acc[1]); o_acc[1] = MFMA(pa1, vr3, o_acc[1]);
        o_acc[2] = MFMA(pa0, vr4, o_acc[2]); o_acc[2] = MFMA(pa1, vr5, o_acc[2]);
        o_acc[3] = MFMA(pa0, vr6, o_acc[3]); o_acc[3] = MFMA(pa1, vr7, o_acc[3]);
        // QK(jj)
#pragma unroll
        for (int nc = 0; nc < 4; ++nc) {
            bf16x8 k0f = frag(KT[cur], nc * 16 + l, quad);
            bf16x8 k1f = frag(KT[cur], nc * 16 + l, 4 + quad);
            s[nc] = MFMA(k0f, qf0, fz);
            s[nc] = MFMA(k1f, qf1, s[nc]);
        }
        __builtin_amdgcn_s_setprio(0);

        // softmax(jj) -> P -> pa regs (consumed next iteration)
#pragma unroll
        for (int nc = 0; nc < 4; ++nc) {
            unsigned w = (nc < 2) ? w0 : w1;
            int bbase = (nc & 1) * 16 + quad * 4;
            bf16x4 pv;
#pragma unroll
            for (int r = 0; r < 4; ++r) {
                float e = __builtin_amdgcn_exp2f(s[nc][r]);
                pv[r] = (bf16)(((w >> (bbase + r)) & 1u) ? e : 0.f);
            }
            *(bf16x4*)&Pb[pidx(l, nc * 16 + quad * 4)] = pv;
        }
        pa0 = *(const bf16x8*)&Pb[pidx(l, quad * 8)];
        pa1 = *(const bf16x8*)&Pb[pidx(l, 32 + quad * 8)];
    }

    // epilogue: PV(NT-1); V(NT-1) still in VT[(NT-1)&1] (never overwritten)
    {
        const bf16* Vp = VT[(NT - 1) & 1];
        __builtin_amdgcn_s_setprio(1);
        l_acc = MFMA(pa0, ones, l_acc);
        l_acc = MFMA(pa1, ones, l_acc);
#pragma unroll
        for (int dc = 0; dc < 4; ++dc) {
            bf16x8 vb0 = frag(Vp, dc * 16 + l, quad);
            bf16x8 vb1 = frag(Vp, dc * 16 + l, 4 + quad);
            o_acc[dc] = MFMA(pa0, vb0, o_acc[dc]);
            o_acc[dc] = MFMA(pa1, vb1, o_acc[dc]);
        }
        __builtin_amdgcn_s_setprio(0);
    }

    size_t pb = ((size_t)((bh * 32 + it) * 2 + jc)) * 4096;
#pragma unroll
    for (int dc = 0; dc < 4; ++dc)
#pragma unroll
        for (int r = 0; r < 4; ++r)
            Opart[pb + (size_t)(rg * 16 + quad * 4 + r) * 64 + dc * 16 + l] = o_acc[dc][r];
    if (l == 0) {
#pragma unroll
        for (int r = 0; r < 4; ++r)
            Lpart[((bh * 32 + it) * 2 + jc) * 64 + rg * 16 + quad * 4 + r] = l_acc[r];
    }
}

// ---------------- combine partials -> normalized split-bf16 O (jc=2) ---------------
__global__ __launch_bounds__(256) void attn_combine(
    const float* __restrict__ Opart, const float* __restrict__ Lpart,
    bf16* __restrict__ Oh, bf16* __restrict__ Ol)
{
    int blk = blockIdx.x;
    int bh = blk >> 5, it = blk & 31;
    int t = threadIdx.x;
    int row = t >> 2, dseg = (t & 3) << 4;

    float acc[16] = {};
    float lsum = 0.f;
#pragma unroll
    for (int jc = 0; jc < 2; ++jc) {
        const float* Op = Opart + ((size_t)(blk * 2 + jc)) * 4096 + (size_t)row * 64 + dseg;
#pragma unroll
        for (int u = 0; u < 4; ++u) {
            float4 v = *(const float4*)&Op[u * 4];
            acc[u * 4 + 0] += v.x; acc[u * 4 + 1] += v.y;
            acc[u * 4 + 2] += v.z; acc[u * 4 + 3] += v.w;
        }
        lsum += Lpart[(blk * 2 + jc) * 64 + row];
    }
    float inv = 1.0f / lsum;
    int b = bh >> 3, h = bh & 7, tok = it * 64 + row;
    size_t base = ((size_t)b * 2048 + tok) * 512 + h * 64 + dseg;
    bf16x8 oh0, oh1, ol0, ol1;
#pragma unroll
    for (int u = 0; u < 8; ++u) {
        float v0 = acc[u] * inv, v1 = acc[8 + u] * inv;
        bf16 h0 = (bf16)v0, h1 = (bf16)v1;
        oh0[u] = h0; ol0[u] = (bf16)(v0 - (float)h0);
        oh1[u] = h1; ol1[u] = (bf16)(v1 - (float)h1);
    }
    *(bf16x8*)&Oh[base] = oh0;
    *(bf16x8*)&Oh[base + 8] = oh1;
    *(bf16x8*)&Ol[base] = ol0;
    *(bf16x8*)&Ol[base + 8] = ol1;
}

// ---------------- output projection, LDS-staged split-bf16 (R3-exact) --------------
__global__ __launch_bounds__(256) void gemm_out(
    const bf16* __restrict__ Ah, const bf16* __restrict__ Al,
    const bf16* __restrict__ Wh, const bf16* __restrict__ Wl,
    float* __restrict__ C)
{
    __shared__ bf16 AhT[4096], AlT[4096], WhT[4096], WlT[4096];
    int bid = blockIdx.x;
    int m0b = bid & 63, n0 = bid >> 6;
    int t = threadIdx.x, wave = t >> 6, lane = t & 63, l = lane & 15, quad = lane >> 4;
    int m0 = m0b * 64 + wave * 16;
    int nb = n0 * 64;
    f32x4 acc[4] = {};
    for (int k0 = 0; k0 < 512; k0 += 64) {
        __syncthreads();
        stage_async(AhT, Ah + (size_t)m0b * 64 * 512 + k0, 512, t);
        stage_async(AlT, Al + (size_t)m0b * 64 * 512 + k0, 512, t);
        stage_async(WhT, Wh + (size_t)nb * 512 + k0, 512, t);
        stage_async(WlT, Wl + (size_t)nb * 512 + k0, 512, t);
        __syncthreads();
        bf16x8 ah0 = frag(AhT, wave * 16 + l, quad);
        bf16x8 ah1 = frag(AhT, wave * 16 + l, 4 + quad);
        bf16x8 al0 = frag(AlT, wave * 16 + l, quad);
        bf16x8 al1 = frag(AlT, wave * 16 + l, 4 + quad);
#pragma unroll
        for (int nc = 0; nc < 4; ++nc) {
            bf16x8 bh0 = frag(WhT, nc * 16 + l, quad);
            bf16x8 bh1 = frag(WhT, nc * 16 + l, 4 + quad);
            bf16x8 bl0 = frag(WlT, nc * 16 + l, quad);
            bf16x8 bl1 = frag(WlT, nc * 16 + l, 4 + quad);
            acc[nc] = MFMA(ah0, bh0, acc[nc]);
            acc[nc] = MFMA(ah1, bh1, acc[nc]);
            acc[nc] = MFMA(ah0, bl0, acc[nc]);
            acc[nc] = MFMA(ah1, bl1, acc[nc]);
            acc[nc] = MFMA(al0, bh0, acc[nc]);
            acc[nc] = MFMA(al1, bh1, acc[nc]);
        }
    }
#pragma unroll
    for (int nc = 0; nc < 4; ++nc)
#pragma unroll
        for (int r = 0; r < 4; ++r)
            C[(size_t)(m0 + quad * 4 + r) * 512 + nb + nc * 16 + l] = acc[nc][r];
}

extern "C" void kernel_launch(void* const* d_in, const int* in_sizes, int n_in,
                              void* d_out, int out_size, void* d_ws, size_t ws_size,
                              hipStream_t stream) {
    const float* x = (const float*)d_in[0];
    const float* Wq = (const float*)d_in[1];
    const float* Wk = (const float*)d_in[2];
    const float* Wv = (const float*)d_in[3];
    const float* Wo = (const float*)d_in[4];
    const int* seqm = (const int*)d_in[5];
    const int* spm = (const int*)d_in[6];
    float* out = (float*)d_out;

    const size_t E = 2097152;            // 2*2048*512
    bf16* xb = (bf16*)d_ws;
    bf16* Wb = xb + E;
    bf16* Woh = Wb + 786432;
    bf16* Wol = Woh + 262144;
    bf16* Qg = Wol + 262144;
    bf16* Kg = Qg + E;
    bf16* Vtg = Kg + E;                  // [bh][64][2048]
    bf16* Ohb = Vtg + E;
    bf16* Olb = Ohb + E;
    unsigned* pseq = (unsigned*)(Olb + E);
    unsigned* psp = pseq + 262144;
    float* Opart = (float*)(psp + 262144);       // 1024 x 4096 fp32 = 16 MB
    float* Lpart = Opart + (size_t)1024 * 4096;  // 0.25 MB

    hipLaunchKernelGGL(prep, dim3(3584), dim3(256), 0, stream,
                       seqm, spm, x, Wq, Wk, Wv, Wo, pseq, psp, xb, Wb, Woh, Wol);
    hipLaunchKernelGGL(gemm_qkv, dim3(768), dim3(256), 0, stream, xb, Wb, Qg, Kg, Vtg);
    hipLaunchKernelGGL(attn_kernel, dim3(1024), dim3(256), 0, stream,
                       Qg, Kg, Vtg, pseq, psp, Opart, Lpart);
    hipLaunchKernelGGL(attn_combine, dim3(512), dim3(256), 0, stream, Opart, Lpart, Ohb, Olb);
    hipLaunchKernelGGL(gemm_out, dim3(512), dim3(256), 0, stream, Ohb, Olb, Woh, Wol, out);
}